// Round 7
// baseline (130.590 us; speedup 1.0000x reference)
//
#include <hip/hip_runtime.h>
#include <hip/hip_bf16.h>

typedef unsigned int u32;
typedef __attribute__((ext_vector_type(8))) short bf16x8;    // 8 bf16 = 4 VGPRs (MFMA A/B frag)
typedef __attribute__((ext_vector_type(16))) float f32x16;   // MFMA C/D frag
typedef __attribute__((ext_vector_type(4))) u32 u32x4;

// ---------------------------------------------------------------------------
// PillarFeatureNet fused (round 15: shared per-pair butterfly + readlane)
//
// R14 PASSED (absmax 0.125) -> DPP xor1/2/4/8 mirrors are HW-proven; the
// R11/R13 2.25 bug was permlane16_swap (my model of it). Proven prim set:
// DPP quad_perm/mirrors, ds_swizzle 0x401F, __shfl_xor(,32), readlane,
// lane-local fragments, scalar np/coors.
//
// R14 cost structure: FOUR butterfly chains per body (one per pillar, each
// useful in only half its lanes) = 48 DPP + 12 swizzle. This round: ONE
// butterfly per PAIR — feed `half ? qB : qA` so lanes<32 compute pillar A's
// sums and lanes>=32 pillar B's (32-groups independent in DPP rows and the
// 0x1F swizzle). Pillar A's p2/p3 (built by lanes<32) use the in-register
// sums; pillar B's take 3x v_readlane(.,32) SGPR broadcasts; lanes>=32
// build only p4 (no centroid). Per body: -24 DPP, -6 swizzles (DS 16->10).
// Everything else identical to passing R14.
// ---------------------------------------------------------------------------

#define XOFF (0.08f)            // vx/2 + pc_range[0]
#define YOFF (0.08f - 39.68f)   // vy/2 + pc_range[1]

// xor-butterfly swizzle within 32-lane groups: offset=(xor<<10)|0x1F (proven)
#define SWZ_ADD(s, imm)                                                        \
    s += __builtin_bit_cast(float, __builtin_amdgcn_ds_swizzle(                \
             __builtin_bit_cast(int, s), imm))

// DPP butterfly-add stage (pure VALU; proven R14)
template <int CTRL>
__device__ __forceinline__ float dpp_add(float s) {
    int t = __builtin_amdgcn_update_dpp(0, __builtin_bit_cast(int, s),
                                        CTRL, 0xF, 0xF, true);
    return s + __builtin_bit_cast(float, t);
}
#define DPP_XOR1  0xB1   // quad_perm [1,0,3,2]
#define DPP_XOR2  0x4E   // quad_perm [2,3,0,1]
#define DPP_HMIRR 0x141  // row_half_mirror (== xor4 once 4-groups uniform)
#define DPP_MIRR  0x140  // row_mirror      (== xor8 once 8-groups uniform)

__device__ __forceinline__ float readlane32f(float v) {
    return __builtin_bit_cast(float,
        __builtin_amdgcn_readlane(__builtin_bit_cast(int, v), 32));
}

__device__ __forceinline__ u32 f2bf_bits(float f) {
    union { float f; u32 u; } v; v.f = f;
    u32 u = v.u;
    u += 0x7fffu + ((u >> 16) & 1u);   // RNE
    return u >> 16;
}
__device__ __forceinline__ short bf1(float f) { return (short)f2bf_bits(f); }

// packed bf16 convert: v_cvt_pk_bf16_f32 (1 instr); lo -> low 16 bits
__device__ __forceinline__ u32 pk2(float lo, float hi) {
    __hip_bfloat162 h = __float22bfloat162_rn(make_float2(lo, hi));
    union { __hip_bfloat162 h; u32 u; } v; v.h = h;
    return v.u;
}

// 16-way max as max3-fusable linear chain
__device__ __forceinline__ float vmax16(const f32x16 v) {
    float m = fmaxf(fmaxf(v[0], v[1]), v[2]);
    m = fmaxf(fmaxf(m, v[3]), v[4]);
    m = fmaxf(fmaxf(m, v[5]), v[6]);
    m = fmaxf(fmaxf(m, v[7]), v[8]);
    m = fmaxf(fmaxf(m, v[9]), v[10]);
    m = fmaxf(fmaxf(m, v[11]), v[12]);
    m = fmaxf(fmaxf(m, v[13]), v[14]);
    return fmaxf(m, v[15]);
}

// ONE butterfly for the pair: lanes<32 sum pillar A's points, lanes>=32
// pillar B's. Outputs: VGPR sums (A-valid in lanes<32) + SGPR-broadcast
// B sums via readlane(32).
__device__ __forceinline__ void centroid_pair(const float4 qa, const float4 qb,
                                              const int half,
                                              float& sxA, float& syA, float& szA,
                                              float& sxB, float& syB, float& szB)
{
    float sx = half ? qb.x : qa.x;
    float sy = half ? qb.y : qa.y;
    float sz = half ? qb.z : qa.z;
    sx = dpp_add<DPP_XOR1>(sx);  sy = dpp_add<DPP_XOR1>(sy);  sz = dpp_add<DPP_XOR1>(sz);
    sx = dpp_add<DPP_XOR2>(sx);  sy = dpp_add<DPP_XOR2>(sy);  sz = dpp_add<DPP_XOR2>(sz);
    sx = dpp_add<DPP_HMIRR>(sx); sy = dpp_add<DPP_HMIRR>(sy); sz = dpp_add<DPP_HMIRR>(sz);
    sx = dpp_add<DPP_MIRR>(sx);  sy = dpp_add<DPP_MIRR>(sy);  sz = dpp_add<DPP_MIRR>(sz);
    SWZ_ADD(sx, 0x401F);         SWZ_ADD(sy, 0x401F);         SWZ_ADD(sz, 0x401F);
    sxA = sx; syA = sy; szA = sz;             // lanes<32: pillar A full sum
    sxB = readlane32f(sx);                    // lane 32: pillar B full sum
    syB = readlane32f(sy);
    szB = readlane32f(sz);
}

// Build the A-fragment for ONE pillar, fully lane-locally (layout proven:
// lanes<32 = {p0..p3} (k0-7), lanes>=32 = {p4,0,0,0} (k8-9), row = lane&31).
// sx/sy/sz: this pillar's point-sum (must be valid in lanes<32; lanes>=32
// only build p4 which doesn't use the centroid).
__device__ __forceinline__ bf16x8 build_frag(const float4 q, const int npts,
                                             const int2 cc, const int m,
                                             const int half,
                                             const float sx, const float sy,
                                             const float sz)
{
    const float rnp = __builtin_amdgcn_rcpf((float)npts);
    const float mx = sx * rnp, my = sy * rnp, mz = sz * rnp;
    const float cxo = (float)cc.y * 0.16f + XOFF;
    const float cyo = (float)cc.x * 0.16f + YOFF;
    const bool  v   = (m < npts);

    u32 p0 = pk2(q.x, q.y);
    u32 p1 = pk2(q.z, q.w);
    u32 p2 = pk2(q.x - mx, q.y - my);
    u32 p3 = pk2(q.z - mz, q.x - cxo);
    if (!v) { p0 = 0; p1 = 0; p2 = 0; p3 = 0; }
    const u32 p4 = pk2(v ? q.y - cyo : 0.0f, 1.0f);   // k9 = bias col (all rows)

    u32x4 w;
    w[0] = half ? p4 : p0;
    w[1] = half ? 0u : p1;
    w[2] = half ? 0u : p2;
    w[3] = half ? 0u : p3;
    return __builtin_bit_cast(bf16x8, w);
}

// back-end: MFMA, pooled max (R8-proven pre-select merge), store one pair
__device__ __forceinline__ void backend(const bf16x8 aA, const bf16x8 aB,
                                        const bf16x8 b0, const bf16x8 b1,
                                        const f32x16 zacc, const int half,
                                        const int lane,
                                        const float npAf, const float npBf,
                                        const int pairIdx, const int n_pairs,
                                        const int n_total,
                                        float* __restrict__ out)
{
    const f32x16 cA0 = __builtin_amdgcn_mfma_f32_32x32x16_bf16(aA, b0, zacc, 0, 0, 0);
    const f32x16 cA1 = __builtin_amdgcn_mfma_f32_32x32x16_bf16(aA, b1, zacc, 0, 0, 0);
    const float tA0 = vmax16(cA0);
    const float tA1 = vmax16(cA1);
    const f32x16 cB0 = __builtin_amdgcn_mfma_f32_32x32x16_bf16(aB, b0, zacc, 0, 0, 0);
    const f32x16 cB1 = __builtin_amdgcn_mfma_f32_32x32x16_bf16(aB, b1, zacc, 0, 0, 0);
    const float tB0 = vmax16(cB0);
    const float tB1 = vmax16(cB1);

    // pre-select merge (proven): keep the tile this lane outputs, send the
    // tile the partner outputs; one exchange per pillar.
    const float keepA = half ? tA1 : tA0, sendA = half ? tA0 : tA1;
    const float keepB = half ? tB1 : tB0, sendB = half ? tB0 : tB1;
    float vA = fmaxf(fmaxf(keepA, __shfl_xor(sendA, 32)), 0.0f);   // relu
    float vB = fmaxf(fmaxf(keepB, __shfl_xor(sendB, 32)), 0.0f);

    // channel 63 = num_points (wave-uniform scalars — no cross-lane op)
    if (lane == 63) { vA = npAf; vB = npBf; }

    if (pairIdx < n_pairs) {
        const int nA = pairIdx * 2;
        out[nA * 64 + lane] = vA;
        if (nA + 1 < n_total) out[(nA + 1) * 64 + lane] = vB;
    }
}

__global__ __launch_bounds__(256, 4)
void pfn_mfma(const float* __restrict__ features,
              const int* __restrict__ num_points,
              const int* __restrict__ coors,
              const float* __restrict__ W,
              const float* __restrict__ gamma,
              const float* __restrict__ beta,
              const float* __restrict__ rmean,
              const float* __restrict__ rvar,
              float* __restrict__ out,
              int n_total)
{
    const int lane = threadIdx.x & 63;
    const int wid  = threadIdx.x >> 6;
    const int half = lane >> 5;          // which k-half of the A-fragment
    const int m    = lane & 31;          // point index / channel within tile
    const int waves_total = gridDim.x * 4;
    const int gwave = blockIdx.x * 4 + wid;

    // ---- per-wave setup: fold BN scale AND shift into W ------------------
    const int c0 = m, c1 = 32 + m;       // tile0 ch 0..31, tile1 ch 32..63
    const float inv0   = gamma[c0] / sqrtf(rvar[c0] + 1e-3f);
    const float shift0 = beta[c0] - rmean[c0] * inv0;
    float inv1 = 0.0f, shift1 = 0.0f;
    if (c1 < 63) {
        inv1   = gamma[c1] / sqrtf(rvar[c1] + 1e-3f);
        shift1 = beta[c1] - rmean[c1] * inv1;
    }

    // B[k][n]: n = lane&31, k = half*8 + j; k<9 weights, k==9 BN shift
    bf16x8 b0, b1;
#pragma unroll
    for (int j = 0; j < 8; ++j) {
        const int k = half * 8 + j;
        float w0v = 0.0f, w1v = 0.0f;
        if (k < 9)       { w0v = W[c0 * 9 + k] * inv0;
                           w1v = (c1 < 63) ? W[c1 * 9 + k] * inv1 : 0.0f; }
        else if (k == 9) { w0v = shift0; w1v = shift1; }
        b0[j] = bf1(w0v);
        b1[j] = bf1(w1v);
    }

    const f32x16 zacc = {};              // hoisted accumulator zero
    const float4* featv = reinterpret_cast<const float4*>(features);
    const int n_pairs = (n_total + 1) >> 1;
    const int stride  = waves_total * 2;               // 2 pairs per body
    const int iters   = (n_pairs + stride - 1) / stride;

    // clamped dual-pillar load: ALL lanes load both pillars' point m.
    // Pillar indices wave-uniform -> np/coors scalar loads; feature loads
    // have lanes l and l+32 on the same address (coalescer merges).
    auto load_pair = [&](int pr, float4& qA, float4& qB,
                         int& npA, int& npB, int2& cA, int2& cB) {
        const int base = min(pr, n_pairs - 1) * 2;
        const int nA = base;
        const int nB = min(base + 1, n_total - 1);
        npA = num_points[nA];
        npB = num_points[nB];
        cA  = *reinterpret_cast<const int2*>(coors + nA * 4 + 2);   // [y, x]
        cB  = *reinterpret_cast<const int2*>(coors + nB * 4 + 2);
        qA  = featv[nA * 32 + m];
        qB  = featv[nB * 32 + m];
    };

    int pa = gwave;                      // pair 1; pair 2 = pa + waves_total
    float4 qa1, qb1, qa2, qb2;
    int na1, nb1, na2, nb2;
    int2 ca1, cb1, ca2, cb2;
    load_pair(pa,               qa1, qb1, na1, nb1, ca1, cb1);
    load_pair(pa + waves_total, qa2, qb2, na2, nb2, ca2, cb2);

    for (int it = 0; it < iters; ++it) {
        // ---- prefetch next body's two pairs (clamped, branchless) --------
        float4 qa1n, qb1n, qa2n, qb2n;
        int na1n, nb1n, na2n, nb2n;
        int2 ca1n, cb1n, ca2n, cb2n;
        load_pair(pa + stride,               qa1n, qb1n, na1n, nb1n, ca1n, cb1n);
        load_pair(pa + stride + waves_total, qa2n, qb2n, na2n, nb2n, ca2n, cb2n);

        // ---- shared butterfly per pair (2 chains/body, indep -> ILP) -----
        float sxA1, syA1, szA1, sxB1, syB1, szB1;
        float sxA2, syA2, szA2, sxB2, syB2, szB2;
        centroid_pair(qa1, qb1, half, sxA1, syA1, szA1, sxB1, syB1, szB1);
        centroid_pair(qa2, qb2, half, sxA2, syA2, szA2, sxB2, syB2, szB2);

        // ---- fragment build: fully lane-local ----------------------------
        const bf16x8 aA1 = build_frag(qa1, na1, ca1, m, half, sxA1, syA1, szA1);
        const bf16x8 aB1 = build_frag(qb1, nb1, cb1, m, half, sxB1, syB1, szB1);
        const bf16x8 aA2 = build_frag(qa2, na2, ca2, m, half, sxA2, syA2, szA2);
        const bf16x8 aB2 = build_frag(qb2, nb2, cb2, m, half, sxB2, syB2, szB2);

        // ---- back-ends (pairwise MFMA keeps <=32 acc regs live) ----------
        backend(aA1, aB1, b0, b1, zacc, half, lane, (float)na1, (float)nb1,
                pa,               n_pairs, n_total, out);
        backend(aA2, aB2, b0, b1, zacc, half, lane, (float)na2, (float)nb2,
                pa + waves_total, n_pairs, n_total, out);

        // rotate
        pa += stride;
        qa1 = qa1n; qb1 = qb1n; na1 = na1n; nb1 = nb1n; ca1 = ca1n; cb1 = cb1n;
        qa2 = qa2n; qb2 = qb2n; na2 = na2n; nb2 = nb2n; ca2 = ca2n; cb2 = cb2n;
    }
}

extern "C" void kernel_launch(void* const* d_in, const int* in_sizes, int n_in,
                              void* d_out, int out_size, void* d_ws, size_t ws_size,
                              hipStream_t stream) {
    const float* features   = (const float*)d_in[0];
    const int*   num_points = (const int*)d_in[1];
    const int*   coors      = (const int*)d_in[2];
    const float* W          = (const float*)d_in[3];
    const float* gamma      = (const float*)d_in[4];
    const float* beta       = (const float*)d_in[5];
    const float* rmean      = (const float*)d_in[6];
    const float* rvar       = (const float*)d_in[7];
    float* out              = (float*)d_out;

    const int n_total = in_sizes[1];   // N pillars

    // 2048 blocks x 4 waves = 8192 waves (traffic-clean per R6);
    // body = 2 pairs -> ~3.7 bodies/wave.
    const int blocks = 2048;
    pfn_mfma<<<blocks, 256, 0, stream>>>(features, num_points, coors, W,
                                         gamma, beta, rmean, rvar, out, n_total);
}

// Round 9
// 127.313 us; speedup vs baseline: 1.0257x; 1.0257x over previous
//
#include <hip/hip_runtime.h>
#include <hip/hip_bf16.h>

typedef unsigned int u32;
typedef __attribute__((ext_vector_type(8))) short bf16x8;    // 8 bf16 = 4 VGPRs (MFMA A/B frag)
typedef __attribute__((ext_vector_type(16))) float f32x16;   // MFMA C/D frag
typedef __attribute__((ext_vector_type(4))) u32 u32x4;

// ---------------------------------------------------------------------------
// PillarFeatureNet fused (round 17: R16 resubmit — infra failure, not a
// kernel verdict)
//
// R16 theory (untested due to container failure): the R8(126.8us) ->
// R14/R15(130.0/130.6us) regression tracks the DUAL feature load introduced
// in R13 (every lane loads both pillars' float4; lanes l and l+32 same
// address): 2x VMEM instruction issue + 2x L1 requests on the dominant
// 61MB stream. Recombine proven-best halves:
//  - split load (R8): one float4 per lane (own half's pillar)
//  - butterfly (R15): DPP xor1/2/4/8 + single ds_swizzle 0x401F per pair,
//    each 32-group sums its own pillar (all prims HW-proven)
//  - fragment build: R8's VERBATIM proven 5x __shfl_xor(,32) exchange +
//    pre-select word assignment
//  - scalar np/coors + per-half select; ch63 from wave-uniform scalars
// DS ops/body: 20 (R8: 46). VMEM: half of R15. No new primitives.
// ---------------------------------------------------------------------------

#define XOFF (0.08f)            // vx/2 + pc_range[0]
#define YOFF (0.08f - 39.68f)   // vy/2 + pc_range[1]

// xor-butterfly swizzle within 32-lane groups: offset=(xor<<10)|0x1F (proven)
#define SWZ_ADD(s, imm)                                                        \
    s += __builtin_bit_cast(float, __builtin_amdgcn_ds_swizzle(                \
             __builtin_bit_cast(int, s), imm))

// DPP butterfly-add stage (pure VALU; proven R14/R15)
template <int CTRL>
__device__ __forceinline__ float dpp_add(float s) {
    int t = __builtin_amdgcn_update_dpp(0, __builtin_bit_cast(int, s),
                                        CTRL, 0xF, 0xF, true);
    return s + __builtin_bit_cast(float, t);
}
#define DPP_XOR1  0xB1   // quad_perm [1,0,3,2]
#define DPP_XOR2  0x4E   // quad_perm [2,3,0,1]
#define DPP_HMIRR 0x141  // row_half_mirror (== xor4 once 4-groups uniform)
#define DPP_MIRR  0x140  // row_mirror      (== xor8 once 8-groups uniform)

__device__ __forceinline__ u32 f2bf_bits(float f) {
    union { float f; u32 u; } v; v.f = f;
    u32 u = v.u;
    u += 0x7fffu + ((u >> 16) & 1u);   // RNE
    return u >> 16;
}
__device__ __forceinline__ short bf1(float f) { return (short)f2bf_bits(f); }

// packed bf16 convert: v_cvt_pk_bf16_f32 (1 instr); lo -> low 16 bits
__device__ __forceinline__ u32 pk2(float lo, float hi) {
    __hip_bfloat162 h = __float22bfloat162_rn(make_float2(lo, hi));
    union { __hip_bfloat162 h; u32 u; } v; v.h = h;
    return v.u;
}

// 16-way max as max3-fusable linear chain
__device__ __forceinline__ float vmax16(const f32x16 v) {
    float m = fmaxf(fmaxf(v[0], v[1]), v[2]);
    m = fmaxf(fmaxf(m, v[3]), v[4]);
    m = fmaxf(fmaxf(m, v[5]), v[6]);
    m = fmaxf(fmaxf(m, v[7]), v[8]);
    m = fmaxf(fmaxf(m, v[9]), v[10]);
    m = fmaxf(fmaxf(m, v[11]), v[12]);
    m = fmaxf(fmaxf(m, v[13]), v[14]);
    return fmaxf(m, v[15]);
}

// front-end: own-pillar features -> both A-fragments via proven exchange.
// q = own half's pillar point m; np/cc = own pillar's scalars (selected).
__device__ __forceinline__ void frontend(const float4 q, const int npts,
                                         const int2 cc, const int m,
                                         const int half,
                                         bf16x8& aA, bf16x8& aB)
{
    // centroid of own pillar: each 32-group independent.
    // DPP xor1/2/4/8 (proven) + single swizzle xor16 (proven).
    float sx = q.x, sy = q.y, sz = q.z;
    sx = dpp_add<DPP_XOR1>(sx);  sy = dpp_add<DPP_XOR1>(sy);  sz = dpp_add<DPP_XOR1>(sz);
    sx = dpp_add<DPP_XOR2>(sx);  sy = dpp_add<DPP_XOR2>(sy);  sz = dpp_add<DPP_XOR2>(sz);
    sx = dpp_add<DPP_HMIRR>(sx); sy = dpp_add<DPP_HMIRR>(sy); sz = dpp_add<DPP_HMIRR>(sz);
    sx = dpp_add<DPP_MIRR>(sx);  sy = dpp_add<DPP_MIRR>(sy);  sz = dpp_add<DPP_MIRR>(sz);
    SWZ_ADD(sx, 0x401F);         SWZ_ADD(sy, 0x401F);         SWZ_ADD(sz, 0x401F);

    const float rnp = __builtin_amdgcn_rcpf((float)npts);
    const float mx = sx * rnp, my = sy * rnp, mz = sz * rnp;
    const float cxo = (float)cc.y * 0.16f + XOFF;
    const float cyo = (float)cc.x * 0.16f + YOFF;

    u32 p0 = pk2(q.x, q.y);
    u32 p1 = pk2(q.z, q.w);
    u32 p2 = pk2(q.x - mx, q.y - my);
    u32 p3 = pk2(q.z - mz, q.x - cxo);
    if (m >= npts) { p0 = 0; p1 = 0; p2 = 0; p3 = 0; }
    const u32 p4 = pk2((m < npts) ? q.y - cyo : 0.0f, 1.0f);   // k9 bias col

    // cross-half exchange + pre-select (VERBATIM R8, proven):
    const u32 x0 = __shfl_xor(p0, 32);
    const u32 x1 = __shfl_xor(p1, 32);
    const u32 x2 = __shfl_xor(p2, 32);
    const u32 x3 = __shfl_xor(p3, 32);
    const u32 x4 = __shfl_xor(p4, 32);

    u32x4 adw, bdw;
    adw[0] = half ? x4 : p0;  adw[1] = half ? 0u : p1;
    adw[2] = half ? 0u : p2;  adw[3] = half ? 0u : p3;
    bdw[0] = half ? p4 : x0;  bdw[1] = half ? 0u : x1;
    bdw[2] = half ? 0u : x2;  bdw[3] = half ? 0u : x3;
    aA = __builtin_bit_cast(bf16x8, adw);
    aB = __builtin_bit_cast(bf16x8, bdw);
}

// back-end: MFMA, pooled max (proven pre-select merge), store one pair
__device__ __forceinline__ void backend(const bf16x8 aA, const bf16x8 aB,
                                        const bf16x8 b0, const bf16x8 b1,
                                        const f32x16 zacc, const int half,
                                        const int lane,
                                        const float npAf, const float npBf,
                                        const int pairIdx, const int n_pairs,
                                        const int n_total,
                                        float* __restrict__ out)
{
    const f32x16 cA0 = __builtin_amdgcn_mfma_f32_32x32x16_bf16(aA, b0, zacc, 0, 0, 0);
    const f32x16 cA1 = __builtin_amdgcn_mfma_f32_32x32x16_bf16(aA, b1, zacc, 0, 0, 0);
    const float tA0 = vmax16(cA0);
    const float tA1 = vmax16(cA1);
    const f32x16 cB0 = __builtin_amdgcn_mfma_f32_32x32x16_bf16(aB, b0, zacc, 0, 0, 0);
    const f32x16 cB1 = __builtin_amdgcn_mfma_f32_32x32x16_bf16(aB, b1, zacc, 0, 0, 0);
    const float tB0 = vmax16(cB0);
    const float tB1 = vmax16(cB1);

    // pre-select merge (proven): keep the tile this lane outputs, send the
    // tile the partner outputs; one exchange per pillar.
    const float keepA = half ? tA1 : tA0, sendA = half ? tA0 : tA1;
    const float keepB = half ? tB1 : tB0, sendB = half ? tB0 : tB1;
    float vA = fmaxf(fmaxf(keepA, __shfl_xor(sendA, 32)), 0.0f);   // relu
    float vB = fmaxf(fmaxf(keepB, __shfl_xor(sendB, 32)), 0.0f);

    // channel 63 = num_points (wave-uniform scalars — proven R14/R15)
    if (lane == 63) { vA = npAf; vB = npBf; }

    if (pairIdx < n_pairs) {
        const int nA = pairIdx * 2;
        out[nA * 64 + lane] = vA;
        if (nA + 1 < n_total) out[(nA + 1) * 64 + lane] = vB;
    }
}

__global__ __launch_bounds__(256, 4)
void pfn_mfma(const float* __restrict__ features,
              const int* __restrict__ num_points,
              const int* __restrict__ coors,
              const float* __restrict__ W,
              const float* __restrict__ gamma,
              const float* __restrict__ beta,
              const float* __restrict__ rmean,
              const float* __restrict__ rvar,
              float* __restrict__ out,
              int n_total)
{
    const int lane = threadIdx.x & 63;
    const int wid  = threadIdx.x >> 6;
    const int half = lane >> 5;          // 0 = pillar A, 1 = pillar B
    const int m    = lane & 31;          // point index / channel within tile
    const int waves_total = gridDim.x * 4;
    const int gwave = blockIdx.x * 4 + wid;

    // ---- per-wave setup: fold BN scale AND shift into W ------------------
    const int c0 = m, c1 = 32 + m;       // tile0 ch 0..31, tile1 ch 32..63
    const float inv0   = gamma[c0] / sqrtf(rvar[c0] + 1e-3f);
    const float shift0 = beta[c0] - rmean[c0] * inv0;
    float inv1 = 0.0f, shift1 = 0.0f;
    if (c1 < 63) {
        inv1   = gamma[c1] / sqrtf(rvar[c1] + 1e-3f);
        shift1 = beta[c1] - rmean[c1] * inv1;
    }

    // B[k][n]: n = lane&31, k = half*8 + j; k<9 weights, k==9 BN shift
    bf16x8 b0, b1;
#pragma unroll
    for (int j = 0; j < 8; ++j) {
        const int k = half * 8 + j;
        float w0v = 0.0f, w1v = 0.0f;
        if (k < 9)       { w0v = W[c0 * 9 + k] * inv0;
                           w1v = (c1 < 63) ? W[c1 * 9 + k] * inv1 : 0.0f; }
        else if (k == 9) { w0v = shift0; w1v = shift1; }
        b0[j] = bf1(w0v);
        b1[j] = bf1(w1v);
    }

    const f32x16 zacc = {};              // hoisted accumulator zero
    const float4* featv = reinterpret_cast<const float4*>(features);
    const int n_pairs = (n_total + 1) >> 1;
    const int stride  = waves_total * 2;               // 2 pairs per body
    const int iters   = (n_pairs + stride - 1) / stride;

    // split load: ONE float4 per lane (own half's pillar); np/coors are
    // wave-uniform scalar loads for both pillars, selected per-half.
    auto load_pair = [&](int pr, float4& q, int& npA, int& npB,
                         int2& cA, int2& cB) {
        const int base = min(pr, n_pairs - 1) * 2;
        const int nA = base;
        const int nB = min(base + 1, n_total - 1);
        npA = num_points[nA];
        npB = num_points[nB];
        cA  = *reinterpret_cast<const int2*>(coors + nA * 4 + 2);   // [y, x]
        cB  = *reinterpret_cast<const int2*>(coors + nB * 4 + 2);
        const int nh = half ? nB : nA;
        q = featv[nh * 32 + m];
    };

    int pa = gwave;                      // pair 1; pair 2 = pa + waves_total
    float4 q1, q2;
    int na1, nb1, na2, nb2;
    int2 ca1, cb1, ca2, cb2;
    load_pair(pa,               q1, na1, nb1, ca1, cb1);
    load_pair(pa + waves_total, q2, na2, nb2, ca2, cb2);

    for (int it = 0; it < iters; ++it) {
        // ---- prefetch next body's two pairs (clamped, branchless) --------
        float4 q1n, q2n;
        int na1n, nb1n, na2n, nb2n;
        int2 ca1n, cb1n, ca2n, cb2n;
        load_pair(pa + stride,               q1n, na1n, nb1n, ca1n, cb1n);
        load_pair(pa + stride + waves_total, q2n, na2n, nb2n, ca2n, cb2n);

        // per-half selected scalars for own pillar
        const int np1 = half ? nb1 : na1;
        const int np2 = half ? nb2 : na2;
        const int2 cc1 = half ? cb1 : ca1;
        const int2 cc2 = half ? cb2 : ca2;

        // ---- two independent front-end chains (scheduler interleaves) ----
        bf16x8 aA1, aB1, aA2, aB2;
        frontend(q1, np1, cc1, m, half, aA1, aB1);
        frontend(q2, np2, cc2, m, half, aA2, aB2);

        // ---- back-ends (pairwise MFMA keeps <=32 acc regs live) ----------
        backend(aA1, aB1, b0, b1, zacc, half, lane, (float)na1, (float)nb1,
                pa,               n_pairs, n_total, out);
        backend(aA2, aB2, b0, b1, zacc, half, lane, (float)na2, (float)nb2,
                pa + waves_total, n_pairs, n_total, out);

        // rotate
        pa += stride;
        q1 = q1n; na1 = na1n; nb1 = nb1n; ca1 = ca1n; cb1 = cb1n;
        q2 = q2n; na2 = na2n; nb2 = nb2n; ca2 = ca2n; cb2 = cb2n;
    }
}

extern "C" void kernel_launch(void* const* d_in, const int* in_sizes, int n_in,
                              void* d_out, int out_size, void* d_ws, size_t ws_size,
                              hipStream_t stream) {
    const float* features   = (const float*)d_in[0];
    const int*   num_points = (const int*)d_in[1];
    const int*   coors      = (const int*)d_in[2];
    const float* W          = (const float*)d_in[3];
    const float* gamma      = (const float*)d_in[4];
    const float* beta       = (const float*)d_in[5];
    const float* rmean      = (const float*)d_in[6];
    const float* rvar       = (const float*)d_in[7];
    float* out              = (float*)d_out;

    const int n_total = in_sizes[1];   // N pillars

    // 2048 blocks x 4 waves = 8192 waves (traffic-clean per R6);
    // body = 2 pairs -> ~3.7 bodies/wave.
    const int blocks = 2048;
    pfn_mfma<<<blocks, 256, 0, stream>>>(features, num_points, coors, W,
                                         gamma, beta, rmean, rvar, out, n_total);
}